// Round 12
// baseline (2311.632 us; speedup 1.0000x reference)
//
#include <hip/hip_runtime.h>
#include <hip/hip_bf16.h>

#define TSTEPS 512
#define NEX 256
#define NIN 128
#define HDIM 256
#define NCOLS 16
#define NROWBLK 16
#define FASTLIM 2048     // bounded fast-poll rounds before sticky fallback

typedef __attribute__((ext_vector_type(8))) short short8;   // 8 bf16 (MFMA A/B frag)
typedef __attribute__((ext_vector_type(4))) float f32x4;    // MFMA C/D frag
typedef __attribute__((ext_vector_type(4))) int i32x4;      // VGPR quad for asm payloads

__device__ __forceinline__ float sig_(float x) {
    return __builtin_amdgcn_rcpf(1.0f + __builtin_amdgcn_exp2f(-1.44269504f * x));
}
__device__ __forceinline__ float tanh_(float x) {
    return 1.0f - 2.0f * __builtin_amdgcn_rcpf(1.0f + __builtin_amdgcn_exp2f(2.88539008f * x));
}

__global__ void zero_ws(unsigned int* p, int n) {
    int i = blockIdx.x * blockDim.x + threadIdx.x;
    if (i < n) p[i] = 0u;
}

// one-time X pre-pack (R8-proven): X[ex][ii][t] f32 -> xp[t][ex][o] bf16
__global__ __launch_bounds__(64) void pack_x(const float* __restrict__ X,
                                             unsigned short* __restrict__ xp) {
    __shared__ __align__(16) unsigned short Ls[16][136];
    const int tid = threadIdx.x;
    const int ex = blockIdx.x >> 5;
    const int t0 = (blockIdx.x & 31) * 16;
#pragma unroll
    for (int s = 0; s < 8; ++s) {
        const int idx = s * 64 + tid;
        const int ii = idx >> 2, tq = idx & 3;
        const float4 v = *(const float4*)(X + ((size_t)ex * NIN + ii) * TSTEPS + t0 + tq * 4);
        const int o = ((ii >> 3) & 3) * 32 + (ii >> 5) * 8 + (ii & 7);
        __hip_bfloat16 b0 = (__hip_bfloat16)v.x, b1 = (__hip_bfloat16)v.y,
                       b2 = (__hip_bfloat16)v.z, b3 = (__hip_bfloat16)v.w;
        Ls[tq * 4 + 0][o] = *(unsigned short*)&b0;
        Ls[tq * 4 + 1][o] = *(unsigned short*)&b1;
        Ls[tq * 4 + 2][o] = *(unsigned short*)&b2;
        Ls[tq * 4 + 3][o] = *(unsigned short*)&b3;
    }
    __syncthreads();
#pragma unroll
    for (int s = 0; s < 4; ++s) {
        const int idx = s * 64 + tid;
        const int tl = idx >> 4, c = idx & 15;
        const short8 v = *(const short8*)&Ls[tl][c * 8];
        *(short8*)(xp + ((size_t)(t0 + tl) * NEX + ex) * NIN + c * 8) = v;
    }
}

// 16-message load (256B per lane), SYS: system-scope (IF$, proven) vs L2-scope (fast).
template<bool SYS>
__device__ __forceinline__ void msg_load16(const char* sb, i32x4* mi) {
    if (SYS) {
        asm volatile(
            "global_load_dwordx4 %0, %16, off sc0 sc1\n\t"
            "global_load_dwordx4 %1, %16, off offset:16 sc0 sc1\n\t"
            "global_load_dwordx4 %2, %16, off offset:128 sc0 sc1\n\t"
            "global_load_dwordx4 %3, %16, off offset:144 sc0 sc1\n\t"
            "global_load_dwordx4 %4, %16, off offset:256 sc0 sc1\n\t"
            "global_load_dwordx4 %5, %16, off offset:272 sc0 sc1\n\t"
            "global_load_dwordx4 %6, %16, off offset:384 sc0 sc1\n\t"
            "global_load_dwordx4 %7, %16, off offset:400 sc0 sc1\n\t"
            "global_load_dwordx4 %8, %16, off offset:512 sc0 sc1\n\t"
            "global_load_dwordx4 %9, %16, off offset:528 sc0 sc1\n\t"
            "global_load_dwordx4 %10, %16, off offset:640 sc0 sc1\n\t"
            "global_load_dwordx4 %11, %16, off offset:656 sc0 sc1\n\t"
            "global_load_dwordx4 %12, %16, off offset:768 sc0 sc1\n\t"
            "global_load_dwordx4 %13, %16, off offset:784 sc0 sc1\n\t"
            "global_load_dwordx4 %14, %16, off offset:896 sc0 sc1\n\t"
            "global_load_dwordx4 %15, %16, off offset:912 sc0 sc1\n\t"
            "s_waitcnt vmcnt(0)"
            : "=&v"(mi[0]), "=&v"(mi[1]), "=&v"(mi[2]), "=&v"(mi[3]),
              "=&v"(mi[4]), "=&v"(mi[5]), "=&v"(mi[6]), "=&v"(mi[7]),
              "=&v"(mi[8]), "=&v"(mi[9]), "=&v"(mi[10]), "=&v"(mi[11]),
              "=&v"(mi[12]), "=&v"(mi[13]), "=&v"(mi[14]), "=&v"(mi[15])
            : "v"(sb) : "memory");
    } else {
        asm volatile(
            "global_load_dwordx4 %0, %16, off sc0\n\t"
            "global_load_dwordx4 %1, %16, off offset:16 sc0\n\t"
            "global_load_dwordx4 %2, %16, off offset:128 sc0\n\t"
            "global_load_dwordx4 %3, %16, off offset:144 sc0\n\t"
            "global_load_dwordx4 %4, %16, off offset:256 sc0\n\t"
            "global_load_dwordx4 %5, %16, off offset:272 sc0\n\t"
            "global_load_dwordx4 %6, %16, off offset:384 sc0\n\t"
            "global_load_dwordx4 %7, %16, off offset:400 sc0\n\t"
            "global_load_dwordx4 %8, %16, off offset:512 sc0\n\t"
            "global_load_dwordx4 %9, %16, off offset:528 sc0\n\t"
            "global_load_dwordx4 %10, %16, off offset:640 sc0\n\t"
            "global_load_dwordx4 %11, %16, off offset:656 sc0\n\t"
            "global_load_dwordx4 %12, %16, off offset:768 sc0\n\t"
            "global_load_dwordx4 %13, %16, off offset:784 sc0\n\t"
            "global_load_dwordx4 %14, %16, off offset:896 sc0\n\t"
            "global_load_dwordx4 %15, %16, off offset:912 sc0\n\t"
            "s_waitcnt vmcnt(0)"
            : "=&v"(mi[0]), "=&v"(mi[1]), "=&v"(mi[2]), "=&v"(mi[3]),
              "=&v"(mi[4]), "=&v"(mi[5]), "=&v"(mi[6]), "=&v"(mi[7]),
              "=&v"(mi[8]), "=&v"(mi[9]), "=&v"(mi[10]), "=&v"(mi[11]),
              "=&v"(mi[12]), "=&v"(mi[13]), "=&v"(mi[14]), "=&v"(mi[15])
            : "v"(sb) : "memory");
    }
}

__device__ __forceinline__ unsigned int tagmin16(const i32x4* mi) {
    const unsigned int* u = (const unsigned int*)mi;
    unsigned int mn = 0xFFFFFFFFu;
#pragma unroll
    for (int q = 0; q < 16; ++q) {
        const unsigned int lo = u[4 * q + 1] < u[4 * q + 3] ? u[4 * q + 1] : u[4 * q + 3];
        mn = mn < lo ? mn : lo;
    }
    return mn;
}

// Persistent LSTM, dual-scope message protocol.
// 256 blocks = 16 unit-tiles x 16 ex-columns; block b: i=b>>4 (u0), j=b&15 (e0).
// Column j's blocks are b==j (mod 16) -> same residue mod 8 -> same XCD under
// round-robin dispatch -> they share one L2 (SPEED assumption only).
// Message: 16B [h01|tag|h23|tag] per producer-lane (8B self-validating halves).
// Producer: plain store (-> shared L2 fast copy) + sc0 sc1 store (-> IF$ truth).
// Consumer: poll sc0-only (L2 latency); if FASTLIM rounds expire, STICKY-switch to
// the R11-proven sc0 sc1 (IF$) poll -> hang structurally impossible.
// x fragments prefetched in the publish shadow; x-MFMAs run pre-poll (wait window).
template<int PX>
__global__ __launch_bounds__(64, 1) void lstm_persist(
    const float* __restrict__ X,     // [256,128,512]
    const float* __restrict__ Wih,   // [1024,128]
    const float* __restrict__ Whh,   // [1024,256]
    const float* __restrict__ bias,  // [1024]
    float* __restrict__ A,           // [512,256,256]
    float* __restrict__ C,           // [512,256,256]
    char* __restrict__ hbuf2,        // [2][256][64] x 16B messages = 512 KB
    const unsigned short* __restrict__ xp)   // [512][256][128] packed bf16 frags
{
    __shared__ __align__(16) __hip_bfloat16 Ws[4][16][392];  // 50.2 KB

    const int tid = threadIdx.x;
    const int b = blockIdx.x;
    const int i = b >> 4, j = b & 15;
    const int u0 = i * 16, e0 = j * 16;

    // one-time weight staging: fp32 -> bf16 LDS [gate][unit_local][k]
    for (int idx = tid; idx < 64 * 96; idx += 64) {
        const int row = idx / 96, q = idx - row * 96;
        const int g = row >> 4, ul = row & 15;
        float4 v;
        int k0;
        if (q < 64) {
            v = *(const float4*)(Whh + (size_t)(g * HDIM + u0 + ul) * HDIM + 4 * q);
            k0 = 4 * q;
        } else {
            v = *(const float4*)(Wih + (size_t)(g * HDIM + u0 + ul) * NIN + 4 * (q - 64));
            k0 = HDIM + 4 * (q - 64);
        }
        Ws[g][ul][k0 + 0] = (__hip_bfloat16)v.x;
        Ws[g][ul][k0 + 1] = (__hip_bfloat16)v.y;
        Ws[g][ul][k0 + 2] = (__hip_bfloat16)v.z;
        Ws[g][ul][k0 + 3] = (__hip_bfloat16)v.w;
    }
    __syncthreads();

    const int mrow = tid & 15;          // D col -> ex_local
    const int kg   = tid >> 4;          // D rows (kg*4+r) -> unit_local
    const int ex   = e0 + mrow;
    const int ub   = u0 + kg * 4;

    short8 wf0[12], wf1[12], wf2[12], wf3[12];
#pragma unroll
    for (int kk = 0; kk < 12; ++kk) {
        wf0[kk] = *(const short8*)&Ws[0][mrow][kk * 32 + kg * 8];
        wf1[kk] = *(const short8*)&Ws[1][mrow][kk * 32 + kg * 8];
        wf2[kk] = *(const short8*)&Ws[2][mrow][kk * 32 + kg * 8];
        wf3[kk] = *(const short8*)&Ws[3][mrow][kk * 32 + kg * 8];
    }
    float bsr[4][4];
#pragma unroll
    for (int g = 0; g < 4; ++g)
#pragma unroll
        for (int r = 0; r < 4; ++r)
            bsr[g][r] = 2.0f * bias[g * HDIM + ub + r];

    const f32x4 Z4 = {0.f, 0.f, 0.f, 0.f};
    float cr[4] = {0.f, 0.f, 0.f, 0.f};

    const size_t cons_off = (size_t)ex * 1024 + (size_t)kg * 32;
    const size_t prod_off = (size_t)ex * 1024 + (size_t)(i * 4 + kg) * 16;

#define X_GATHER(dst, tt)                                                          \
    {                                                                              \
        const float* xb = X + (size_t)ex * NIN * TSTEPS + (tt);                    \
        _Pragma("unroll")                                                          \
        for (int kk = 0; kk < 4; ++kk) {                                           \
            union { __hip_bfloat16 hh[8]; short8 v; } uxx;                         \
            _Pragma("unroll")                                                      \
            for (int e = 0; e < 8; ++e)                                            \
                uxx.hh[e] = (__hip_bfloat16)xb[(size_t)(kk * 32 + kg * 8 + e) * TSTEPS]; \
            (dst)[kk] = uxx.v;                                                     \
        }                                                                          \
    }

    // prologue: x fragments for t=0
    short8 xf[4];
    if (PX) {
        const unsigned short* xrow = xp + ((size_t)0 * NEX + ex) * NIN + kg * 32;
#pragma unroll
        for (int kk = 0; kk < 4; ++kk) xf[kk] = *(const short8*)(xrow + kk * 8);
    } else {
        X_GATHER(xf, 0);
    }

    bool sticky = false;   // per-block: false = L2 fast poll, true = IF$ proven poll

    for (int t = 0; t < TSTEPS; ++t) {
        // ---- x-part MFMAs: pre-poll (inside the wait window, off critical path) ----
        f32x4 a0 = Z4, a1 = Z4, a2 = Z4, a3 = Z4;
#pragma unroll
        for (int kk = 0; kk < 4; ++kk) {
            a0 = __builtin_amdgcn_mfma_f32_16x16x32_bf16(wf0[8 + kk], xf[kk], a0, 0, 0, 0);
            a1 = __builtin_amdgcn_mfma_f32_16x16x32_bf16(wf1[8 + kk], xf[kk], a1, 0, 0, 0);
            a2 = __builtin_amdgcn_mfma_f32_16x16x32_bf16(wf2[8 + kk], xf[kk], a2, 0, 0, 0);
            a3 = __builtin_amdgcn_mfma_f32_16x16x32_bf16(wf3[8 + kk], xf[kk], a3, 0, 0, 0);
        }

        if (t > 0) {
            const char* sb = hbuf2 + (size_t)((t - 1) & 1) * (NEX * 64 * 16) + cons_off;
            i32x4 m[16];
            if (!sticky) {
                int rounds = 0;
                for (;;) {
                    msg_load16<false>(sb, m);                     // L2-scope poll
                    if (__all(tagmin16(m) == (unsigned int)t)) break;
                    if (++rounds > FASTLIM) { sticky = true; break; }
                }
            }
            if (sticky) {
                for (;;) {
                    msg_load16<true>(sb, m);                      // IF$-scope (proven)
                    if (__all(tagmin16(m) == (unsigned int)t)) break;
                }
            }
            // ---- h-part MFMAs: zh[kk] from msgs 2kk,2kk+1 (h01 at u[0], h23 at u[2]) ----
            const unsigned int* mu = (const unsigned int*)m;
#pragma unroll
            for (int kk = 0; kk < 8; ++kk) {
                union { unsigned int u[4]; short8 v; } z;
                z.u[0] = mu[4 * (2 * kk) + 0];
                z.u[1] = mu[4 * (2 * kk) + 2];
                z.u[2] = mu[4 * (2 * kk + 1) + 0];
                z.u[3] = mu[4 * (2 * kk + 1) + 2];
                a0 = __builtin_amdgcn_mfma_f32_16x16x32_bf16(wf0[kk], z.v, a0, 0, 0, 0);
                a1 = __builtin_amdgcn_mfma_f32_16x16x32_bf16(wf1[kk], z.v, a1, 0, 0, 0);
                a2 = __builtin_amdgcn_mfma_f32_16x16x32_bf16(wf2[kk], z.v, a2, 0, 0, 0);
                a3 = __builtin_amdgcn_mfma_f32_16x16x32_bf16(wf3[kk], z.v, a3, 0, 0, 0);
            }
        }

        // ---- pointwise cell ----
        float hr[4];
#pragma unroll
        for (int r = 0; r < 4; ++r) {
            const float gi = sig_(a0[r] + bsr[0][r]);
            const float gf = sig_(a1[r] + bsr[1][r]);
            const float gg = tanh_(a2[r] + bsr[2][r]);
            const float go = sig_(a3[r] + bsr[3][r]);
            cr[r] = gf * cr[r] + gi * gg;
            hr[r] = go * tanh_(cr[r]);
        }

        // ---- publish: plain store (L2 fast copy) + sc0 sc1 store (IF$ truth) ----
        union { unsigned int u[4]; i32x4 i4; } P;
        __hip_bfloat162 p01(__float2bfloat16(hr[0]), __float2bfloat16(hr[1]));
        __hip_bfloat162 p23(__float2bfloat16(hr[2]), __float2bfloat16(hr[3]));
        P.u[0] = *(unsigned int*)&p01;
        P.u[1] = (unsigned int)(t + 1);
        P.u[2] = *(unsigned int*)&p23;
        P.u[3] = (unsigned int)(t + 1);
        char* dst = hbuf2 + (size_t)(t & 1) * (NEX * 64 * 16) + prod_off;
        asm volatile("global_store_dwordx4 %0, %1, off\n\t"
                     "global_store_dwordx4 %0, %1, off sc0 sc1"
                     :: "v"(dst), "v"(P.i4) : "memory");

        // ---- shadow: outputs + x(t+1) prefetch (drained by next poll's vmcnt) ----
        const size_t off = (size_t)t * NEX * HDIM + (size_t)ex * HDIM + ub;
        *(float4*)&A[off] = make_float4(hr[0], hr[1], hr[2], hr[3]);
        *(float4*)&C[off] = make_float4(cr[0], cr[1], cr[2], cr[3]);
        if (t + 1 < TSTEPS) {
            if (PX) {
                const unsigned short* xrow = xp + ((size_t)(t + 1) * NEX + ex) * NIN + kg * 32;
#pragma unroll
                for (int kk = 0; kk < 4; ++kk) xf[kk] = *(const short8*)(xrow + kk * 8);
            } else {
                X_GATHER(xf, t + 1);
            }
        }
    }
#undef X_GATHER
}

extern "C" void kernel_launch(void* const* d_in, const int* in_sizes, int n_in,
                              void* d_out, int out_size, void* d_ws, size_t ws_size,
                              hipStream_t stream) {
    const float* X   = (const float*)d_in[0];
    const float* Wih = (const float*)d_in[1];
    const float* Whh = (const float*)d_in[2];
    const float* b   = (const float*)d_in[3];
    float* A = (float*)d_out;
    float* C = A + (size_t)TSTEPS * NEX * HDIM;

    const size_t hbuf_bytes = (size_t)2 * NEX * 64 * 16;                           // 512 KB
    const size_t xp_bytes   = (size_t)TSTEPS * NEX * NIN * sizeof(unsigned short); // 32 MB

    char* hbuf2 = (char*)d_ws;
    unsigned short* xpw = (unsigned short*)((char*)d_ws + hbuf_bytes);
    const bool px = ws_size >= hbuf_bytes + xp_bytes;

    const int nzero = (int)(hbuf_bytes / 4);
    zero_ws<<<(nzero + 255) / 256, 256, 0, stream>>>((unsigned int*)hbuf2, nzero);
    if (px) pack_x<<<dim3(NEX * 32), dim3(64), 0, stream>>>(X, xpw);

    const unsigned short* xpc = xpw;
    if (px) {
        void* args[] = {(void*)&X, (void*)&Wih, (void*)&Whh, (void*)&b,
                        (void*)&A, (void*)&C, (void*)&hbuf2, (void*)&xpc};
        hipError_t err = hipLaunchCooperativeKernel((const void*)lstm_persist<1>,
                                                    dim3(256), dim3(64), args, 0, stream);
        if (err != hipSuccess) {
            lstm_persist<1><<<dim3(256), dim3(64), 0, stream>>>(X, Wih, Whh, b, A, C, hbuf2, xpc);
        }
    } else {
        void* args[] = {(void*)&X, (void*)&Wih, (void*)&Whh, (void*)&b,
                        (void*)&A, (void*)&C, (void*)&hbuf2, (void*)&xpc};
        hipError_t err = hipLaunchCooperativeKernel((const void*)lstm_persist<0>,
                                                    dim3(256), dim3(64), args, 0, stream);
        if (err != hipSuccess) {
            lstm_persist<0><<<dim3(256), dim3(64), 0, stream>>>(X, Wih, Whh, b, A, C, hbuf2, xpc);
        }
    }
}

// Round 13
// 1340.461 us; speedup vs baseline: 1.7245x; 1.7245x over previous
//
#include <hip/hip_runtime.h>
#include <hip/hip_bf16.h>

#define TSTEPS 512
#define NEX 256
#define NIN 128
#define HDIM 256
#define NCOLS 16
#define NROWBLK 16

typedef __attribute__((ext_vector_type(8))) short short8;   // 8 bf16 (MFMA A/B frag)
typedef __attribute__((ext_vector_type(4))) float f32x4;    // MFMA C/D frag
typedef __attribute__((ext_vector_type(4))) int i32x4;      // VGPR quad for asm payloads

__device__ __forceinline__ float sig_(float x) {
    return __builtin_amdgcn_rcpf(1.0f + __builtin_amdgcn_exp2f(-1.44269504f * x));
}
__device__ __forceinline__ float tanh_(float x) {
    return 1.0f - 2.0f * __builtin_amdgcn_rcpf(1.0f + __builtin_amdgcn_exp2f(2.88539008f * x));
}

__global__ void zero_ws(unsigned int* p, int n) {
    int i = blockIdx.x * blockDim.x + threadIdx.x;
    if (i < n) p[i] = 0u;
}

// one-time X pre-pack (R8-proven): X[ex][ii][t] f32 -> xp[t][ex][o] bf16
__global__ __launch_bounds__(64) void pack_x(const float* __restrict__ X,
                                             unsigned short* __restrict__ xp) {
    __shared__ __align__(16) unsigned short Ls[16][136];
    const int tid = threadIdx.x;
    const int ex = blockIdx.x >> 5;
    const int t0 = (blockIdx.x & 31) * 16;
#pragma unroll
    for (int s = 0; s < 8; ++s) {
        const int idx = s * 64 + tid;
        const int ii = idx >> 2, tq = idx & 3;
        const float4 v = *(const float4*)(X + ((size_t)ex * NIN + ii) * TSTEPS + t0 + tq * 4);
        const int o = ((ii >> 3) & 3) * 32 + (ii >> 5) * 8 + (ii & 7);
        __hip_bfloat16 b0 = (__hip_bfloat16)v.x, b1 = (__hip_bfloat16)v.y,
                       b2 = (__hip_bfloat16)v.z, b3 = (__hip_bfloat16)v.w;
        Ls[tq * 4 + 0][o] = *(unsigned short*)&b0;
        Ls[tq * 4 + 1][o] = *(unsigned short*)&b1;
        Ls[tq * 4 + 2][o] = *(unsigned short*)&b2;
        Ls[tq * 4 + 3][o] = *(unsigned short*)&b3;
    }
    __syncthreads();
#pragma unroll
    for (int s = 0; s < 4; ++s) {
        const int idx = s * 64 + tid;
        const int tl = idx >> 4, c = idx & 15;
        const short8 v = *(const short8*)&Ls[tl][c * 8];
        *(short8*)(xp + ((size_t)(t0 + tl) * NEX + ex) * NIN + c * 8) = v;
    }
}

// Phase 1: tag-only poll — 16 x dword (tag word of each message), 64B/lane/round.
__device__ __forceinline__ unsigned int tag_poll16(const char* sb) {
    unsigned int tg[16];
    asm volatile(
        "global_load_dword %0, %16, off offset:4 sc0 sc1\n\t"
        "global_load_dword %1, %16, off offset:20 sc0 sc1\n\t"
        "global_load_dword %2, %16, off offset:132 sc0 sc1\n\t"
        "global_load_dword %3, %16, off offset:148 sc0 sc1\n\t"
        "global_load_dword %4, %16, off offset:260 sc0 sc1\n\t"
        "global_load_dword %5, %16, off offset:276 sc0 sc1\n\t"
        "global_load_dword %6, %16, off offset:388 sc0 sc1\n\t"
        "global_load_dword %7, %16, off offset:404 sc0 sc1\n\t"
        "global_load_dword %8, %16, off offset:516 sc0 sc1\n\t"
        "global_load_dword %9, %16, off offset:532 sc0 sc1\n\t"
        "global_load_dword %10, %16, off offset:644 sc0 sc1\n\t"
        "global_load_dword %11, %16, off offset:660 sc0 sc1\n\t"
        "global_load_dword %12, %16, off offset:772 sc0 sc1\n\t"
        "global_load_dword %13, %16, off offset:788 sc0 sc1\n\t"
        "global_load_dword %14, %16, off offset:900 sc0 sc1\n\t"
        "global_load_dword %15, %16, off offset:916 sc0 sc1\n\t"
        "s_waitcnt vmcnt(0)"
        : "=&v"(tg[0]), "=&v"(tg[1]), "=&v"(tg[2]), "=&v"(tg[3]),
          "=&v"(tg[4]), "=&v"(tg[5]), "=&v"(tg[6]), "=&v"(tg[7]),
          "=&v"(tg[8]), "=&v"(tg[9]), "=&v"(tg[10]), "=&v"(tg[11]),
          "=&v"(tg[12]), "=&v"(tg[13]), "=&v"(tg[14]), "=&v"(tg[15])
        : "v"(sb) : "memory");
    unsigned int mn = tg[0];
#pragma unroll
    for (int q = 1; q < 16; ++q) mn = mn < tg[q] ? mn : tg[q];
    return mn;
}

// Phase 2: full message load — 16 x dwordx4 (IF$ scope), R11-proven.
__device__ __forceinline__ void msg_load16(const char* sb, i32x4* mi) {
    asm volatile(
        "global_load_dwordx4 %0, %16, off sc0 sc1\n\t"
        "global_load_dwordx4 %1, %16, off offset:16 sc0 sc1\n\t"
        "global_load_dwordx4 %2, %16, off offset:128 sc0 sc1\n\t"
        "global_load_dwordx4 %3, %16, off offset:144 sc0 sc1\n\t"
        "global_load_dwordx4 %4, %16, off offset:256 sc0 sc1\n\t"
        "global_load_dwordx4 %5, %16, off offset:272 sc0 sc1\n\t"
        "global_load_dwordx4 %6, %16, off offset:384 sc0 sc1\n\t"
        "global_load_dwordx4 %7, %16, off offset:400 sc0 sc1\n\t"
        "global_load_dwordx4 %8, %16, off offset:512 sc0 sc1\n\t"
        "global_load_dwordx4 %9, %16, off offset:528 sc0 sc1\n\t"
        "global_load_dwordx4 %10, %16, off offset:640 sc0 sc1\n\t"
        "global_load_dwordx4 %11, %16, off offset:656 sc0 sc1\n\t"
        "global_load_dwordx4 %12, %16, off offset:768 sc0 sc1\n\t"
        "global_load_dwordx4 %13, %16, off offset:784 sc0 sc1\n\t"
        "global_load_dwordx4 %14, %16, off offset:896 sc0 sc1\n\t"
        "global_load_dwordx4 %15, %16, off offset:912 sc0 sc1\n\t"
        "s_waitcnt vmcnt(0)"
        : "=&v"(mi[0]), "=&v"(mi[1]), "=&v"(mi[2]), "=&v"(mi[3]),
          "=&v"(mi[4]), "=&v"(mi[5]), "=&v"(mi[6]), "=&v"(mi[7]),
          "=&v"(mi[8]), "=&v"(mi[9]), "=&v"(mi[10]), "=&v"(mi[11]),
          "=&v"(mi[12]), "=&v"(mi[13]), "=&v"(mi[14]), "=&v"(mi[15])
        : "v"(sb) : "memory");
}

__device__ __forceinline__ unsigned int tagmin16(const i32x4* mi) {
    const unsigned int* u = (const unsigned int*)mi;
    unsigned int mn = 0xFFFFFFFFu;
#pragma unroll
    for (int q = 0; q < 16; ++q) {
        const unsigned int lo = u[4 * q + 1] < u[4 * q + 3] ? u[4 * q + 1] : u[4 * q + 3];
        mn = mn < lo ? mn : lo;
    }
    return mn;
}

// Persistent LSTM, two-phase message protocol (tag poll + verified data load).
// 256 blocks = 16 unit-tiles x 16 ex-columns; block b: i=b>>4 (u0), j=b&15 (e0).
// Message: 16B [h01|tag|h23|tag] per producer-lane in hbuf2[t&1][ex][g=i*4+kg].
// Publish = ONE sc0 sc1 dwordx4 (IF$-visible, no drain, no separate tag store).
// Consume = tag-only poll (64B/lane/round, 4x less IF$ traffic than R11) until
// min(tag)==t, then ONE fused data load verified on both tag words (retry on tear;
// tears are transient since both 8B halves come from one producer store).
// x-MFMAs run pre-poll (wait window); x prefetch + A/C stores in the publish shadow.
template<int PX>
__global__ __launch_bounds__(64, 1) void lstm_persist(
    const float* __restrict__ X,     // [256,128,512]
    const float* __restrict__ Wih,   // [1024,128]
    const float* __restrict__ Whh,   // [1024,256]
    const float* __restrict__ bias,  // [1024]
    float* __restrict__ A,           // [512,256,256]
    float* __restrict__ C,           // [512,256,256]
    char* __restrict__ hbuf2,        // [2][256][64] x 16B messages = 512 KB
    const unsigned short* __restrict__ xp)   // [512][256][128] packed bf16 frags
{
    __shared__ __align__(16) __hip_bfloat16 Ws[4][16][392];  // 50.2 KB

    const int tid = threadIdx.x;
    const int b = blockIdx.x;
    const int i = b >> 4, j = b & 15;
    const int u0 = i * 16, e0 = j * 16;

    // one-time weight staging: fp32 -> bf16 LDS [gate][unit_local][k]
    for (int idx = tid; idx < 64 * 96; idx += 64) {
        const int row = idx / 96, q = idx - row * 96;
        const int g = row >> 4, ul = row & 15;
        float4 v;
        int k0;
        if (q < 64) {
            v = *(const float4*)(Whh + (size_t)(g * HDIM + u0 + ul) * HDIM + 4 * q);
            k0 = 4 * q;
        } else {
            v = *(const float4*)(Wih + (size_t)(g * HDIM + u0 + ul) * NIN + 4 * (q - 64));
            k0 = HDIM + 4 * (q - 64);
        }
        Ws[g][ul][k0 + 0] = (__hip_bfloat16)v.x;
        Ws[g][ul][k0 + 1] = (__hip_bfloat16)v.y;
        Ws[g][ul][k0 + 2] = (__hip_bfloat16)v.z;
        Ws[g][ul][k0 + 3] = (__hip_bfloat16)v.w;
    }
    __syncthreads();

    const int mrow = tid & 15;          // D col -> ex_local
    const int kg   = tid >> 4;          // D rows (kg*4+r) -> unit_local
    const int ex   = e0 + mrow;
    const int ub   = u0 + kg * 4;

    short8 wf0[12], wf1[12], wf2[12], wf3[12];
#pragma unroll
    for (int kk = 0; kk < 12; ++kk) {
        wf0[kk] = *(const short8*)&Ws[0][mrow][kk * 32 + kg * 8];
        wf1[kk] = *(const short8*)&Ws[1][mrow][kk * 32 + kg * 8];
        wf2[kk] = *(const short8*)&Ws[2][mrow][kk * 32 + kg * 8];
        wf3[kk] = *(const short8*)&Ws[3][mrow][kk * 32 + kg * 8];
    }
    float bsr[4][4];
#pragma unroll
    for (int g = 0; g < 4; ++g)
#pragma unroll
        for (int r = 0; r < 4; ++r)
            bsr[g][r] = 2.0f * bias[g * HDIM + ub + r];

    const f32x4 Z4 = {0.f, 0.f, 0.f, 0.f};
    float cr[4] = {0.f, 0.f, 0.f, 0.f};

    const size_t cons_off = (size_t)ex * 1024 + (size_t)kg * 32;
    const size_t prod_off = (size_t)ex * 1024 + (size_t)(i * 4 + kg) * 16;

#define X_GATHER(dst, tt)                                                          \
    {                                                                              \
        const float* xb = X + (size_t)ex * NIN * TSTEPS + (tt);                    \
        _Pragma("unroll")                                                          \
        for (int kk = 0; kk < 4; ++kk) {                                           \
            union { __hip_bfloat16 hh[8]; short8 v; } uxx;                         \
            _Pragma("unroll")                                                      \
            for (int e = 0; e < 8; ++e)                                            \
                uxx.hh[e] = (__hip_bfloat16)xb[(size_t)(kk * 32 + kg * 8 + e) * TSTEPS]; \
            (dst)[kk] = uxx.v;                                                     \
        }                                                                          \
    }

    // prologue: x fragments for t=0
    short8 xf[4];
    if (PX) {
        const unsigned short* xrow = xp + ((size_t)0 * NEX + ex) * NIN + kg * 32;
#pragma unroll
        for (int kk = 0; kk < 4; ++kk) xf[kk] = *(const short8*)(xrow + kk * 8);
    } else {
        X_GATHER(xf, 0);
    }

    for (int t = 0; t < TSTEPS; ++t) {
        // ---- x-part MFMAs: pre-poll (inside the wait window) ----
        f32x4 a0 = Z4, a1 = Z4, a2 = Z4, a3 = Z4;
#pragma unroll
        for (int kk = 0; kk < 4; ++kk) {
            a0 = __builtin_amdgcn_mfma_f32_16x16x32_bf16(wf0[8 + kk], xf[kk], a0, 0, 0, 0);
            a1 = __builtin_amdgcn_mfma_f32_16x16x32_bf16(wf1[8 + kk], xf[kk], a1, 0, 0, 0);
            a2 = __builtin_amdgcn_mfma_f32_16x16x32_bf16(wf2[8 + kk], xf[kk], a2, 0, 0, 0);
            a3 = __builtin_amdgcn_mfma_f32_16x16x32_bf16(wf3[8 + kk], xf[kk], a3, 0, 0, 0);
        }

        if (t > 0) {
            const char* sb = hbuf2 + (size_t)((t - 1) & 1) * (NEX * 64 * 16) + cons_off;
            i32x4 m[16];
            for (;;) {
                // phase 1: cheap tag poll
                while (!__all(tag_poll16(sb) == (unsigned int)t)) {}
                // phase 2: full data load, verify both tag words (tear check)
                msg_load16(sb, m);
                if (__all(tagmin16(m) == (unsigned int)t)) break;
            }
            // ---- h-part MFMAs ----
            const unsigned int* mu = (const unsigned int*)m;
#pragma unroll
            for (int kk = 0; kk < 8; ++kk) {
                union { unsigned int u[4]; short8 v; } z;
                z.u[0] = mu[4 * (2 * kk) + 0];
                z.u[1] = mu[4 * (2 * kk) + 2];
                z.u[2] = mu[4 * (2 * kk + 1) + 0];
                z.u[3] = mu[4 * (2 * kk + 1) + 2];
                a0 = __builtin_amdgcn_mfma_f32_16x16x32_bf16(wf0[kk], z.v, a0, 0, 0, 0);
                a1 = __builtin_amdgcn_mfma_f32_16x16x32_bf16(wf1[kk], z.v, a1, 0, 0, 0);
                a2 = __builtin_amdgcn_mfma_f32_16x16x32_bf16(wf2[kk], z.v, a2, 0, 0, 0);
                a3 = __builtin_amdgcn_mfma_f32_16x16x32_bf16(wf3[kk], z.v, a3, 0, 0, 0);
            }
        }

        // ---- pointwise cell ----
        float hr[4];
#pragma unroll
        for (int r = 0; r < 4; ++r) {
            const float gi = sig_(a0[r] + bsr[0][r]);
            const float gf = sig_(a1[r] + bsr[1][r]);
            const float gg = tanh_(a2[r] + bsr[2][r]);
            const float go = sig_(a3[r] + bsr[3][r]);
            cr[r] = gf * cr[r] + gi * gg;
            hr[r] = go * tanh_(cr[r]);
        }

        // ---- publish: ONE 16B dual-tag message (sc0 sc1), no drain ----
        union { unsigned int u[4]; i32x4 i4; } P;
        __hip_bfloat162 p01(__float2bfloat16(hr[0]), __float2bfloat16(hr[1]));
        __hip_bfloat162 p23(__float2bfloat16(hr[2]), __float2bfloat16(hr[3]));
        P.u[0] = *(unsigned int*)&p01;
        P.u[1] = (unsigned int)(t + 1);
        P.u[2] = *(unsigned int*)&p23;
        P.u[3] = (unsigned int)(t + 1);
        char* dst = hbuf2 + (size_t)(t & 1) * (NEX * 64 * 16) + prod_off;
        asm volatile("global_store_dwordx4 %0, %1, off sc0 sc1"
                     :: "v"(dst), "v"(P.i4) : "memory");

        // ---- shadow: outputs + x(t+1) prefetch ----
        const size_t off = (size_t)t * NEX * HDIM + (size_t)ex * HDIM + ub;
        *(float4*)&A[off] = make_float4(hr[0], hr[1], hr[2], hr[3]);
        *(float4*)&C[off] = make_float4(cr[0], cr[1], cr[2], cr[3]);
        if (t + 1 < TSTEPS) {
            if (PX) {
                const unsigned short* xrow = xp + ((size_t)(t + 1) * NEX + ex) * NIN + kg * 32;
#pragma unroll
                for (int kk = 0; kk < 4; ++kk) xf[kk] = *(const short8*)(xrow + kk * 8);
            } else {
                X_GATHER(xf, t + 1);
            }
        }
    }
#undef X_GATHER
}

extern "C" void kernel_launch(void* const* d_in, const int* in_sizes, int n_in,
                              void* d_out, int out_size, void* d_ws, size_t ws_size,
                              hipStream_t stream) {
    const float* X   = (const float*)d_in[0];
    const float* Wih = (const float*)d_in[1];
    const float* Whh = (const float*)d_in[2];
    const float* b   = (const float*)d_in[3];
    float* A = (float*)d_out;
    float* C = A + (size_t)TSTEPS * NEX * HDIM;

    const size_t hbuf_bytes = (size_t)2 * NEX * 64 * 16;                           // 512 KB
    const size_t xp_bytes   = (size_t)TSTEPS * NEX * NIN * sizeof(unsigned short); // 32 MB

    char* hbuf2 = (char*)d_ws;
    unsigned short* xpw = (unsigned short*)((char*)d_ws + hbuf_bytes);
    const bool px = ws_size >= hbuf_bytes + xp_bytes;

    const int nzero = (int)(hbuf_bytes / 4);
    zero_ws<<<(nzero + 255) / 256, 256, 0, stream>>>((unsigned int*)hbuf2, nzero);
    if (px) pack_x<<<dim3(NEX * 32), dim3(64), 0, stream>>>(X, xpw);

    const unsigned short* xpc = xpw;
    if (px) {
        void* args[] = {(void*)&X, (void*)&Wih, (void*)&Whh, (void*)&b,
                        (void*)&A, (void*)&C, (void*)&hbuf2, (void*)&xpc};
        hipError_t err = hipLaunchCooperativeKernel((const void*)lstm_persist<1>,
                                                    dim3(256), dim3(64), args, 0, stream);
        if (err != hipSuccess) {
            lstm_persist<1><<<dim3(256), dim3(64), 0, stream>>>(X, Wih, Whh, b, A, C, hbuf2, xpc);
        }
    } else {
        void* args[] = {(void*)&X, (void*)&Wih, (void*)&Whh, (void*)&b,
                        (void*)&A, (void*)&C, (void*)&hbuf2, (void*)&xpc};
        hipError_t err = hipLaunchCooperativeKernel((const void*)lstm_persist<0>,
                                                    dim3(256), dim3(64), args, 0, stream);
        if (err != hipSuccess) {
            lstm_persist<0><<<dim3(256), dim3(64), 0, stream>>>(X, Wih, Whh, b, A, C, hbuf2, xpc);
        }
    }
}